// Round 1
// 173.592 us; speedup vs baseline: 1.0389x; 1.0389x over previous
//
#include <hip/hip_runtime.h>

#define BB 64
#define SS 512
#define DD 768
#define NROWS (BB*SS)   // 32768
#define NEG (-1e30f)
#define NCH 16          // chunks per sequence
#define CL  32          // chunk length (NCH*CL == SS)

// ---------------------------------------------------------------------------
// Kernel 1: masked emissions em = relu((mask? seq.W^T : 0) + b), T=2.
// One wave per 4 rows. Writes em time-major (s,b,2), tags (s,b), labels_m/mask.
// (unchanged from verified baseline)
// ---------------------------------------------------------------------------
__global__ __launch_bounds__(256) void k_emissions(
    const float* __restrict__ seq,
    const int*   __restrict__ input_ids,
    const int*   __restrict__ labels,
    const float* __restrict__ W,
    const float* __restrict__ bias,
    float* __restrict__ em_t,           // ws: (S, B, 2)
    int*   __restrict__ tags_t,         // ws: (S, B)
    float* __restrict__ out)
{
    const int lane = threadIdx.x & 63;
    const int wid  = blockIdx.x * 4 + (threadIdx.x >> 6);
    const int base = wid * 4;

    const float4* W4 = (const float4*)W;
    float4 w0[3], w1[3];
#pragma unroll
    for (int j = 0; j < 3; ++j) {
        w0[j] = W4[j*64 + lane];
        w1[j] = W4[192 + j*64 + lane];
    }
    const float b0 = bias[0], b1 = bias[1];

    const float4* s4 = (const float4*)seq;
    float4 v[4][3];
#pragma unroll
    for (int r = 0; r < 4; ++r)
#pragma unroll
        for (int j = 0; j < 3; ++j)
            v[r][j] = s4[(size_t)(base + r)*192 + j*64 + lane];

    float d0[4], d1[4];
#pragma unroll
    for (int r = 0; r < 4; ++r) {
        float a0 = 0.f, a1 = 0.f;
#pragma unroll
        for (int j = 0; j < 3; ++j) {
            float4 x = v[r][j];
            a0 += x.x*w0[j].x + x.y*w0[j].y + x.z*w0[j].z + x.w*w0[j].w;
            a1 += x.x*w1[j].x + x.y*w1[j].y + x.z*w1[j].z + x.w*w1[j].w;
        }
        d0[r] = a0; d1[r] = a1;
    }
#pragma unroll
    for (int m = 32; m >= 1; m >>= 1) {
#pragma unroll
        for (int r = 0; r < 4; ++r) {
            d0[r] += __shfl_xor(d0[r], m, 64);
            d1[r] += __shfl_xor(d1[r], m, 64);
        }
    }
    if (lane == 0) {
        const int4 idv = *(const int4*)(input_ids + base);
        const int4 lbv = *(const int4*)(labels + base);
        const int ida[4] = {idv.x, idv.y, idv.z, idv.w};
        const int lba[4] = {lbv.x, lbv.y, lbv.z, lbv.w};
#pragma unroll
        for (int r = 0; r < 4; ++r) {
            const int row = base + r;
            const int id = ida[r], lab = lba[r];
            const int msk = (id != 0 && id != 103 && lab != 100) ? 1 : 0;
            const int lm  = lab * msk;
            const float e0 = fmaxf((msk ? d0[r] : 0.f) + b0, 0.f);
            const float e1 = fmaxf((msk ? d1[r] : 0.f) + b1, 0.f);
            const int b_ = row >> 9, s_ = row & 511;
            *(float2*)(em_t + (s_*BB + b_)*2) = make_float2(e0, e1);
            tags_t[s_*BB + b_] = lm;
            out[1 + NROWS   + row] = (float)lm;
            out[1 + 2*NROWS + row] = (float)msk;
        }
    }
}

// ---------------------------------------------------------------------------
// Kernel 2: CRF, grid = 2 blocks x 1024 threads.
//   block 0: loss — EXP-DOMAIN chunk products (2 exp/step instead of 8
//            transcendentals) + periodic renorm, then log-domain combine.
//   block 1: viterbi — max-plus chunk products -> boundary states ->
//            backpointers (+ per-chunk backward-map composition) ->
//            PARALLEL per-chunk backtrack -> bit-packed tags -> writeout.
// wave = chunk (16 chunks of 32 steps), lane = sequence.
// ---------------------------------------------------------------------------
__device__ __forceinline__ float lse2(float x, float y) {
    float m = fmaxf(x, y);
    float d = fminf(x, y) - m;
    return m + __logf(1.f + __expf(d));
}

// exp-domain log-semiring step: row-wise 2x2 product with per-step emission
#define STEP_LE(e_, g_) do { \
    float Ex = __expf((e_).x), Ey = __expf((e_).y); \
    float B00 = X00*Ex, B10 = X10*Ex, B01 = X01*Ey, B11 = X11*Ey; \
    float n00 = fmaf(p00, B00, p01*B10); \
    float n01 = fmaf(p00, B01, p01*B11); \
    float n10 = fmaf(p10, B00, p11*B10); \
    float n11 = fmaf(p10, B01, p11*B11); \
    p00 = n00; p01 = n01; p10 = n10; p11 = n11; \
    score += (ptag ? ((g_) ? t11 : t10) : ((g_) ? t01 : t00)) \
           + ((g_) ? (e_).y : (e_).x); \
    ptag = (g_); \
} while (0)

// per-row renormalization every 8 steps: keeps fp32 well inside range.
// rcp is approximate; the residual scale error (~1e-7) lands in the final
// log and is negligible after /32768.
#define RENORM() do { \
    float m0 = fmaxf(p00, p01), m1 = fmaxf(p10, p11); \
    float r0 = __builtin_amdgcn_rcpf(m0), r1 = __builtin_amdgcn_rcpf(m1); \
    p00 *= r0; p01 *= r0; p10 *= r1; p11 *= r1; \
    lc0 += __logf(m0); lc1 += __logf(m1); \
} while (0)

#define STEP_VP(e_) do { \
    float n0 = fmaxf(V00 + t00, V01 + t10) + (e_).x; \
    float n1 = fmaxf(V00 + t01, V01 + t11) + (e_).y; \
    float n2 = fmaxf(V10 + t00, V11 + t10) + (e_).x; \
    float n3 = fmaxf(V10 + t01, V11 + t11) + (e_).y; \
    V00 = n0; V01 = n1; V10 = n2; V11 = n3; \
} while (0)

// backpointer step i (chunk-local, compile-time): pack bp pair into w0/w1
// registers AND compose the chunk's backward map F (tag@chunk_end ->
// tag@(chunk_start-1)).  F_new(j) = F_old(bp_j).
#define STEP_BPF(i_, e_) do { \
    float c00 = v0 + t00, c10 = v1 + t10; \
    float c01 = v0 + t01, c11 = v1 + t11; \
    int bp0 = (c10 > c00); int bp1 = (c11 > c01); \
    v0 = fmaxf(c00, c10) + (e_).x; v1 = fmaxf(c01, c11) + (e_).y; \
    unsigned two = (unsigned)(bp0 | (bp1 << 1)); \
    if ((i_) < 16) w0 |= two << (2*(i_)); else w1 |= two << (2*((i_)-16)); \
    int nF0 = bp0 ? F1 : F0; int nF1 = bp1 ? F1 : F0; \
    F0 = nF0; F1 = nF1; \
} while (0)

__global__ __launch_bounds__(1024) void k_crf(
    const float* __restrict__ em_t,   // (S,B,2)
    const int*   __restrict__ tags_t, // (S,B)
    const float* __restrict__ start,
    const float* __restrict__ endt,
    const float* __restrict__ trans,
    float* __restrict__ out)
{
    __shared__ float4 logP4[NCH][BB];       // 16 KB (loss)
    __shared__ float  scoreP[NCH][BB];      //  4 KB (loss)
    __shared__ float4 vitP4[NCH][BB];       // 16 KB (viterbi)
    __shared__ float2 vbound[NCH][BB];      //  8 KB (viterbi)
    __shared__ unsigned char Fsh[NCH][BB];  //  1 KB (viterbi chunk maps)
    __shared__ int lastSh[BB];              // 256 B
    __shared__ unsigned int tagbits[BB*17]; //  4.25 KB (padded)

    const int tid = threadIdx.x;
    const int b   = tid & 63;     // sequence
    const int c   = tid >> 6;     // chunk / wave id
    const int k0  = c * CL;
    const float t00 = trans[0], t01 = trans[1], t10 = trans[2], t11 = trans[3];
    const float s0 = start[0], s1 = start[1];
    const float en0 = endt[0], en1 = endt[1];
    const float2* em2 = (const float2*)em_t;

    if (blockIdx.x == 0) {
        // ================= LOSS (exp-domain chunk products) =================
        const float X00 = __expf(t00), X01 = __expf(t01),
                    X10 = __expf(t10), X11 = __expf(t11);
        float2 e[8]; int g[8];
        float p00, p01, p10, p11, lc0 = 0.f, lc1 = 0.f, score;
        int ptag;
#pragma unroll
        for (int i = 0; i < 8; ++i) {
            e[i] = em2[(k0+i)*BB + b];
            g[i] = tags_t[(k0+i)*BB + b];
        }
        if (c == 0) {
            p00 = 1.f; p01 = 0.f; p10 = 0.f; p11 = 1.f;   // identity
            score = g[0] ? (s1 + e[0].y) : (s0 + e[0].x);
        } else {
            int pt = tags_t[(k0-1)*BB + b];
            float Ex = __expf(e[0].x), Ey = __expf(e[0].y);
            p00 = X00*Ex; p01 = X01*Ey; p10 = X10*Ex; p11 = X11*Ey;
            score = (pt ? (g[0] ? t11 : t10) : (g[0] ? t01 : t00))
                  + (g[0] ? e[0].y : e[0].x);
        }
        ptag = g[0];
#pragma unroll
        for (int i = 1; i < 8; ++i) STEP_LE(e[i], g[i]);
        RENORM();
#pragma unroll
        for (int j = 1; j < 4; ++j) {
#pragma unroll
            for (int i = 0; i < 8; ++i) {
                e[i] = em2[(k0 + j*8 + i)*BB + b];
                g[i] = tags_t[(k0 + j*8 + i)*BB + b];
            }
#pragma unroll
            for (int i = 0; i < 8; ++i) STEP_LE(e[i], g[i]);
            RENORM();
        }
        // back to log domain (clamped like the old NEG semantics)
        float P00L = fmaxf(__logf(p00) + lc0, NEG);
        float P01L = fmaxf(__logf(p01) + lc0, NEG);
        float P10L = fmaxf(__logf(p10) + lc1, NEG);
        float P11L = fmaxf(__logf(p11) + lc1, NEG);
        logP4[c][b] = make_float4(P00L, P01L, P10L, P11L);
        scoreP[c][b] = score;
        __syncthreads();
        if (c == 0) {
            float2 em0v = em2[b];
            float a0 = s0 + em0v.x, a1 = s1 + em0v.y, sc = 0.f;
#pragma unroll
            for (int cc = 0; cc < NCH; ++cc) {
                float4 P = logP4[cc][b];
                float n0 = lse2(a0 + P.x, a1 + P.z);
                float n1 = lse2(a0 + P.y, a1 + P.w);
                a0 = n0; a1 = n1;
                sc += scoreP[cc][b];
            }
            int tagL = tags_t[511*BB + b];
            sc += tagL ? en1 : en0;
            float logZ = lse2(a0 + en0, a1 + en1);
            float llh = sc - logZ;
#pragma unroll
            for (int m = 32; m >= 1; m >>= 1) llh += __shfl_xor(llh, m, 64);
            if (b == 0) out[0] = llh / (float)NROWS;
        }
    } else {
        // ================= VITERBI =================
        // phase 1: chunk max-plus products; emissions held in registers
        // across phases (64 VGPR — still <=128/wave at 16 waves/CU).
        float2 e[32];
#pragma unroll
        for (int i = 0; i < 32; ++i) e[i] = em2[(k0+i)*BB + b];
        float V00, V01, V10, V11;
        if (c == 0) {
            V00 = 0.f; V01 = NEG; V10 = NEG; V11 = 0.f;
        } else {
            V00 = t00 + e[0].x; V01 = t01 + e[0].y;
            V10 = t10 + e[0].x; V11 = t11 + e[0].y;
        }
#pragma unroll
        for (int i = 1; i < 32; ++i) STEP_VP(e[i]);
        vitP4[c][b] = make_float4(V00, V01, V10, V11);
        __syncthreads();

        // phase 2: chunk-boundary states + final argmax (one wave, per-lane b)
        if (c == 0) {
            float2 em0v = em2[b];
            float v0 = s0 + em0v.x, v1 = s1 + em0v.y;
            vbound[0][b] = make_float2(v0, v1);
#pragma unroll
            for (int cc = 0; cc < NCH; ++cc) {
                float4 V = vitP4[cc][b];
                float n0 = fmaxf(v0 + V.x, v1 + V.z);
                float n1 = fmaxf(v0 + V.y, v1 + V.w);
                v0 = n0; v1 = n1;
                if (cc < NCH-1) vbound[cc+1][b] = make_float2(v0, v1);
            }
            lastSh[b] = (v1 + en1 > v0 + en0) ? 1 : 0;
        }
        __syncthreads();

        // phase 3: backpointer recompute from register-held emissions;
        // bp pairs packed into w0/w1, chunk backward map composed into F.
        unsigned w0 = 0u, w1 = 0u;
        int F0 = 0, F1 = 1;
        {
            float2 vb = vbound[c][b];
            float v0 = vb.x, v1 = vb.y;
            if (c != 0) STEP_BPF(0, e[0]);
#pragma unroll
            for (int i = 1; i < 32; ++i) STEP_BPF(i, e[i]);
        }
        Fsh[c][b] = (unsigned char)(F0 | (F1 << 1));
        __syncthreads();

        // phase 4: every wave resolves its own chunk-end tag by composing
        // the suffix of chunk maps (<=15 dependent selects), then backtracks
        // its 32 steps in parallel from register-held bp bits.
        {
            int t = lastSh[b];
            for (int cc = NCH-1; cc > c; --cc)    // wave-uniform trip count
                t = (Fsh[cc][b] >> t) & 1;
            unsigned word = ((unsigned)t) << 31;  // tag at position k0+31
#pragma unroll
            for (int i = 31; i >= 1; --i) {
                unsigned pair = ((i >= 16) ? (w1 >> (2*(i-16)))
                                           : (w0 >> (2*i))) & 3u;
                t = (int)((pair >> t) & 1u);
                word |= ((unsigned)t) << (i - 1);
            }
            tagbits[b*17 + c] = word;
        }
        __syncthreads();

        // phase 5: coalesced float writeout of tags
        for (int idx = tid; idx < NROWS; idx += 1024) {
            const int bq = idx >> 9, k = idx & 511;
            unsigned wd = tagbits[bq*17 + (k >> 5)];
            out[1 + idx] = (float)((wd >> (k & 31)) & 1);
        }
    }
}

extern "C" void kernel_launch(void* const* d_in, const int* in_sizes, int n_in,
                              void* d_out, int out_size, void* d_ws, size_t ws_size,
                              hipStream_t stream) {
    const float* seq    = (const float*)d_in[0];
    const int*   ids    = (const int*)  d_in[1];
    const int*   labels = (const int*)  d_in[2];
    const float* W      = (const float*)d_in[3];
    const float* bias   = (const float*)d_in[4];
    const float* start  = (const float*)d_in[5];
    const float* endt   = (const float*)d_in[6];
    const float* trans  = (const float*)d_in[7];
    float* out = (float*)d_out;

    float* em_t   = (float*)d_ws;                                      // 256 KB
    int*   tags_t = (int*)((char*)d_ws + (size_t)65536*sizeof(float)); // 128 KB

    k_emissions<<<2048, 256, 0, stream>>>(seq, ids, labels, W, bias, em_t, tags_t, out);
    k_crf<<<2, 1024, 0, stream>>>(em_t, tags_t, start, endt, trans, out);
}

// Round 2
// 171.935 us; speedup vs baseline: 1.0489x; 1.0096x over previous
//
#include <hip/hip_runtime.h>

#define BB 64
#define SS 512
#define DD 768
#define NROWS (BB*SS)   // 32768
#define NEG (-1e30f)
#define NCH 16          // chunks per sequence
#define CL  32          // chunk length (NCH*CL == SS)

// ---------------------------------------------------------------------------
// Kernel 1: masked emissions em = relu((mask? seq.W^T : 0) + b), T=2.
// One wave per 4 rows. Writes em time-major (s,b,2), tags (s,b), labels_m/mask.
// Epilogue distributed over lanes 0..3 (no runtime-indexed reg arrays).
// ---------------------------------------------------------------------------
__global__ __launch_bounds__(256) void k_emissions(
    const float* __restrict__ seq,
    const int*   __restrict__ input_ids,
    const int*   __restrict__ labels,
    const float* __restrict__ W,
    const float* __restrict__ bias,
    float* __restrict__ em_t,           // ws: (S, B, 2)
    int*   __restrict__ tags_t,         // ws: (S, B)
    float* __restrict__ out)
{
    const int lane = threadIdx.x & 63;
    const int wid  = blockIdx.x * 4 + (threadIdx.x >> 6);
    const int base = wid * 4;

    const float4* W4 = (const float4*)W;
    float4 w0[3], w1[3];
#pragma unroll
    for (int j = 0; j < 3; ++j) {
        w0[j] = W4[j*64 + lane];
        w1[j] = W4[192 + j*64 + lane];
    }
    const float b0 = bias[0], b1 = bias[1];

    const float4* s4 = (const float4*)seq;
    float4 v[4][3];
#pragma unroll
    for (int r = 0; r < 4; ++r)
#pragma unroll
        for (int j = 0; j < 3; ++j)
            v[r][j] = s4[(size_t)(base + r)*192 + j*64 + lane];

    float d0[4], d1[4];
#pragma unroll
    for (int r = 0; r < 4; ++r) {
        float a0 = 0.f, a1 = 0.f;
#pragma unroll
        for (int j = 0; j < 3; ++j) {
            float4 x = v[r][j];
            a0 += x.x*w0[j].x + x.y*w0[j].y + x.z*w0[j].z + x.w*w0[j].w;
            a1 += x.x*w1[j].x + x.y*w1[j].y + x.z*w1[j].z + x.w*w1[j].w;
        }
        d0[r] = a0; d1[r] = a1;
    }
#pragma unroll
    for (int m = 32; m >= 1; m >>= 1) {
#pragma unroll
        for (int r = 0; r < 4; ++r) {
            d0[r] += __shfl_xor(d0[r], m, 64);
            d1[r] += __shfl_xor(d1[r], m, 64);
        }
    }
    // after the full butterfly every lane holds all 8 sums; lanes 0..3
    // each handle one row (compile-time selects, no runtime array index).
    if (lane < 4) {
        const float dd0 = (lane==0) ? d0[0] : (lane==1) ? d0[1] : (lane==2) ? d0[2] : d0[3];
        const float dd1 = (lane==0) ? d1[0] : (lane==1) ? d1[1] : (lane==2) ? d1[2] : d1[3];
        const int row = base + lane;
        const int id  = input_ids[row];
        const int lab = labels[row];
        const int msk = (id != 0 && id != 103 && lab != 100) ? 1 : 0;
        const int lm  = lab * msk;
        const float e0 = fmaxf((msk ? dd0 : 0.f) + b0, 0.f);
        const float e1 = fmaxf((msk ? dd1 : 0.f) + b1, 0.f);
        const int b_ = row >> 9, s_ = row & 511;
        *(float2*)(em_t + (s_*BB + b_)*2) = make_float2(e0, e1);
        tags_t[s_*BB + b_] = lm;
        out[1 + NROWS   + row] = (float)lm;
        out[1 + 2*NROWS + row] = (float)msk;
    }
}

// ---------------------------------------------------------------------------
// CRF helpers (identical arithmetic to the verified round-1 kernel)
// ---------------------------------------------------------------------------
__device__ __forceinline__ float lse2(float x, float y) {
    float m = fmaxf(x, y);
    float d = fminf(x, y) - m;
    return m + __logf(1.f + __expf(d));
}

// exp-domain log-semiring step: row-wise 2x2 product with per-step emission
#define STEP_LE(e_, g_) do { \
    float Ex = __expf((e_).x), Ey = __expf((e_).y); \
    float B00 = X00*Ex, B10 = X10*Ex, B01 = X01*Ey, B11 = X11*Ey; \
    float n00 = fmaf(p00, B00, p01*B10); \
    float n01 = fmaf(p00, B01, p01*B11); \
    float n10 = fmaf(p10, B00, p11*B10); \
    float n11 = fmaf(p10, B01, p11*B11); \
    p00 = n00; p01 = n01; p10 = n10; p11 = n11; \
    score += (ptag ? ((g_) ? t11 : t10) : ((g_) ? t01 : t00)) \
           + ((g_) ? (e_).y : (e_).x); \
    ptag = (g_); \
} while (0)

#define RENORM() do { \
    float m0 = fmaxf(p00, p01), m1 = fmaxf(p10, p11); \
    float r0 = __builtin_amdgcn_rcpf(m0), r1 = __builtin_amdgcn_rcpf(m1); \
    p00 *= r0; p01 *= r0; p10 *= r1; p11 *= r1; \
    lc0 += __logf(m0); lc1 += __logf(m1); \
} while (0)

#define STEP_VP(e_) do { \
    float n0 = fmaxf(V00 + t00, V01 + t10) + (e_).x; \
    float n1 = fmaxf(V00 + t01, V01 + t11) + (e_).y; \
    float n2 = fmaxf(V10 + t00, V11 + t10) + (e_).x; \
    float n3 = fmaxf(V10 + t01, V11 + t11) + (e_).y; \
    V00 = n0; V01 = n1; V10 = n2; V11 = n3; \
} while (0)

#define STEP_BPF(i_, e_) do { \
    float c00 = v0 + t00, c10 = v1 + t10; \
    float c01 = v0 + t01, c11 = v1 + t11; \
    int bp0 = (c10 > c00); int bp1 = (c11 > c01); \
    v0 = fmaxf(c00, c10) + (e_).x; v1 = fmaxf(c01, c11) + (e_).y; \
    unsigned two = (unsigned)(bp0 | (bp1 << 1)); \
    if ((i_) < 16) w0 |= two << (2*(i_)); else w1 |= two << (2*((i_)-16)); \
    int nF0 = bp0 ? F1 : F0; int nF1 = bp1 ? F1 : F0; \
    F0 = nF0; F1 = nF1; \
} while (0)

// ---------------------------------------------------------------------------
// Kernel 2a: chunk products, 16 blocks x 128 threads, one CU per chunk.
//   wave 0: loss chunk product (exp-domain) -> logP4g, scoreg
//   wave 1: viterbi max-plus chunk product -> vitP4g
// 2-wave blocks => ~512 VGPR budget => all 32 loads hoisted into one
// latency window, pure-register 32-step recurrence.
// ---------------------------------------------------------------------------
__global__ __launch_bounds__(128, 1) void k_crf1(
    const float* __restrict__ em_t,   // (S,B,2)
    const int*   __restrict__ tags_t, // (S,B)
    const float* __restrict__ start,
    const float* __restrict__ trans,
    float* __restrict__ logP4g,       // 16*64 float4
    float* __restrict__ scoreg,       // 16*64 float
    float* __restrict__ vitP4g)       // 16*64 float4
{
    const int b  = threadIdx.x & 63;
    const int c  = blockIdx.x;
    const int k0 = c * CL;
    const float t00 = trans[0], t01 = trans[1], t10 = trans[2], t11 = trans[3];
    const float2* em2 = (const float2*)em_t;

    if (threadIdx.x < 64) {
        // ---------------- loss chunk (exp-domain) ----------------
        const float s0 = start[0], s1 = start[1];
        const float X00 = __expf(t00), X01 = __expf(t01),
                    X10 = __expf(t10), X11 = __expf(t11);
        float2 e[32]; int g[32];
#pragma unroll
        for (int i = 0; i < 32; ++i) {
            e[i] = em2[(k0+i)*BB + b];
            g[i] = tags_t[(k0+i)*BB + b];
        }
        float p00, p01, p10, p11, lc0 = 0.f, lc1 = 0.f, score;
        int ptag;
        if (c == 0) {
            p00 = 1.f; p01 = 0.f; p10 = 0.f; p11 = 1.f;   // identity
            score = g[0] ? (s1 + e[0].y) : (s0 + e[0].x);
        } else {
            int pt = tags_t[(k0-1)*BB + b];
            float Ex = __expf(e[0].x), Ey = __expf(e[0].y);
            p00 = X00*Ex; p01 = X01*Ey; p10 = X10*Ex; p11 = X11*Ey;
            score = (pt ? (g[0] ? t11 : t10) : (g[0] ? t01 : t00))
                  + (g[0] ? e[0].y : e[0].x);
        }
        ptag = g[0];
#pragma unroll
        for (int i = 1; i < 32; ++i) {
            STEP_LE(e[i], g[i]);
            if ((i & 7) == 7) RENORM();
        }
        float4 P = make_float4(fmaxf(__logf(p00) + lc0, NEG),
                               fmaxf(__logf(p01) + lc0, NEG),
                               fmaxf(__logf(p10) + lc1, NEG),
                               fmaxf(__logf(p11) + lc1, NEG));
        ((float4*)logP4g)[c*BB + b] = P;
        scoreg[c*BB + b] = score;
    } else {
        // ---------------- viterbi chunk (max-plus) ----------------
        float2 e[32];
#pragma unroll
        for (int i = 0; i < 32; ++i) e[i] = em2[(k0+i)*BB + b];
        float V00, V01, V10, V11;
        if (c == 0) {
            V00 = 0.f; V01 = NEG; V10 = NEG; V11 = 0.f;
        } else {
            V00 = t00 + e[0].x; V01 = t01 + e[0].y;
            V10 = t10 + e[0].x; V11 = t11 + e[0].y;
        }
#pragma unroll
        for (int i = 1; i < 32; ++i) STEP_VP(e[i]);
        ((float4*)vitP4g)[c*BB + b] = make_float4(V00, V01, V10, V11);
    }
}

// ---------------------------------------------------------------------------
// Kernel 2b: combine, 2 blocks x 1024.
//   block 0 (wave 0 only): loss boundary-combine -> out[0]
//   block 1: viterbi boundary chain -> bp recompute (16 waves, streamed em)
//            -> F-map compose -> parallel per-chunk backtrack -> writeout
// ---------------------------------------------------------------------------
__global__ __launch_bounds__(1024) void k_crf2(
    const float* __restrict__ em_t,   // (S,B,2)
    const int*   __restrict__ tags_t, // (S,B)
    const float* __restrict__ start,
    const float* __restrict__ endt,
    const float* __restrict__ trans,
    const float* __restrict__ logP4g,
    const float* __restrict__ scoreg,
    const float* __restrict__ vitP4g,
    float* __restrict__ out)
{
    __shared__ float2 vbound[NCH][BB];      //  8 KB
    __shared__ unsigned char Fsh[NCH][BB];  //  1 KB
    __shared__ int lastSh[BB];              // 256 B
    __shared__ unsigned int tagbits[BB*17]; //  4.25 KB (padded)

    const int tid = threadIdx.x;
    const int b   = tid & 63;     // sequence
    const int c   = tid >> 6;     // chunk / wave id
    const int k0  = c * CL;
    const float t00 = trans[0], t01 = trans[1], t10 = trans[2], t11 = trans[3];
    const float s0 = start[0], s1 = start[1];
    const float en0 = endt[0], en1 = endt[1];
    const float2* em2 = (const float2*)em_t;

    if (blockIdx.x == 0) {
        // ================= LOSS combine =================
        if (c == 0) {
            float2 em0v = em2[b];
            float a0 = s0 + em0v.x, a1 = s1 + em0v.y, sc = 0.f;
#pragma unroll
            for (int cc = 0; cc < NCH; ++cc) {
                float4 P = ((const float4*)logP4g)[cc*BB + b];
                float n0 = lse2(a0 + P.x, a1 + P.z);
                float n1 = lse2(a0 + P.y, a1 + P.w);
                a0 = n0; a1 = n1;
                sc += scoreg[cc*BB + b];
            }
            int tagL = tags_t[511*BB + b];
            sc += tagL ? en1 : en0;
            float logZ = lse2(a0 + en0, a1 + en1);
            float llh = sc - logZ;
#pragma unroll
            for (int m = 32; m >= 1; m >>= 1) llh += __shfl_xor(llh, m, 64);
            if (b == 0) out[0] = llh / (float)NROWS;
        }
    } else {
        // ================= VITERBI finish =================
        // phase 2: chunk-boundary states + final argmax (one wave)
        if (c == 0) {
            float2 em0v = em2[b];
            float v0 = s0 + em0v.x, v1 = s1 + em0v.y;
            vbound[0][b] = make_float2(v0, v1);
#pragma unroll
            for (int cc = 0; cc < NCH; ++cc) {
                float4 V = ((const float4*)vitP4g)[cc*BB + b];
                float n0 = fmaxf(v0 + V.x, v1 + V.z);
                float n1 = fmaxf(v0 + V.y, v1 + V.w);
                v0 = n0; v1 = n1;
                if (cc < NCH-1) vbound[cc+1][b] = make_float2(v0, v1);
            }
            lastSh[b] = (v1 + en1 > v0 + en0) ? 1 : 0;
        }
        __syncthreads();

        // phase 3: backpointer recompute (em streamed in 8-groups, low VGPR)
        unsigned w0 = 0u, w1 = 0u;
        int F0 = 0, F1 = 1;
        {
            float2 vb = vbound[c][b];
            float v0 = vb.x, v1 = vb.y;
            float2 e[8];
#pragma unroll
            for (int i = 0; i < 8; ++i) e[i] = em2[(k0+i)*BB + b];
            if (c != 0) STEP_BPF(0, e[0]);
#pragma unroll
            for (int i = 1; i < 8; ++i) STEP_BPF(i, e[i]);
#pragma unroll
            for (int j = 1; j < 4; ++j) {
#pragma unroll
                for (int i = 0; i < 8; ++i) e[i] = em2[(k0 + j*8 + i)*BB + b];
#pragma unroll
                for (int i = 0; i < 8; ++i) STEP_BPF(j*8 + i, e[i]);
            }
        }
        Fsh[c][b] = (unsigned char)(F0 | (F1 << 1));
        __syncthreads();

        // phase 4: resolve chunk-end tag via suffix of chunk maps, then
        // backtrack 32 steps in parallel from register-held bp bits.
        {
            int t = lastSh[b];
            for (int cc = NCH-1; cc > c; --cc)    // wave-uniform trip count
                t = (Fsh[cc][b] >> t) & 1;
            unsigned word = ((unsigned)t) << 31;  // tag at position k0+31
#pragma unroll
            for (int i = 31; i >= 1; --i) {
                unsigned pair = ((i >= 16) ? (w1 >> (2*(i-16)))
                                           : (w0 >> (2*i))) & 3u;
                t = (int)((pair >> t) & 1u);
                word |= ((unsigned)t) << (i - 1);
            }
            tagbits[b*17 + c] = word;
        }
        __syncthreads();

        // phase 5: coalesced float writeout of tags
        for (int idx = tid; idx < NROWS; idx += 1024) {
            const int bq = idx >> 9, k = idx & 511;
            unsigned wd = tagbits[bq*17 + (k >> 5)];
            out[1 + idx] = (float)((wd >> (k & 31)) & 1);
        }
    }
}

extern "C" void kernel_launch(void* const* d_in, const int* in_sizes, int n_in,
                              void* d_out, int out_size, void* d_ws, size_t ws_size,
                              hipStream_t stream) {
    const float* seq    = (const float*)d_in[0];
    const int*   ids    = (const int*)  d_in[1];
    const int*   labels = (const int*)  d_in[2];
    const float* W      = (const float*)d_in[3];
    const float* bias   = (const float*)d_in[4];
    const float* start  = (const float*)d_in[5];
    const float* endt   = (const float*)d_in[6];
    const float* trans  = (const float*)d_in[7];
    float* out = (float*)d_out;

    float* em_t   = (float*)d_ws;                                     // 256 KB
    int*   tags_t = (int*)  ((char*)d_ws + (size_t) 65536*4);         // 128 KB
    float* logP4g = (float*)((char*)d_ws + (size_t) 98304*4);         //  16 KB
    float* scoreg = (float*)((char*)d_ws + (size_t)102400*4);         //   4 KB
    float* vitP4g = (float*)((char*)d_ws + (size_t)103424*4);         //  16 KB

    k_emissions<<<2048, 256, 0, stream>>>(seq, ids, labels, W, bias, em_t, tags_t, out);
    k_crf1<<<16, 128, 0, stream>>>(em_t, tags_t, start, trans, logP4g, scoreg, vitP4g);
    k_crf2<<<2, 1024, 0, stream>>>(em_t, tags_t, start, endt, trans,
                                   logP4g, scoreg, vitP4g, out);
}